// Round 4
// baseline (153.730 us; speedup 1.0000x reference)
//
#include <hip/hip_runtime.h>
#include <math.h>

typedef float    f4  __attribute__((ext_vector_type(4)));
typedef int      i4  __attribute__((ext_vector_type(4)));
typedef _Float16 hf4 __attribute__((ext_vector_type(4)));

namespace {

constexpr float kA0C0     = 0.8862269254527580f;  // pi / sqrt(4*pi)
constexpr float kA1C1     = 1.7724538509055159f;
constexpr float kA2C2     = 2.4270324670f;
constexpr float kAmbient  = 0.8f;
constexpr float kInvSigma = 1e4f;
constexpr float kInvGamma = 1e4f;
constexpr float kEps      = 1e-10f;
constexpr float kZfar     = 100.0f;
constexpr float kInvZrng  = 1.0f / 99.0f;   // 1/(ZFAR-ZNEAR)
constexpr float kExpCut   = -88.0f;         // exp underflow cutoff (f32)

// ---- Pass A: per-face SH shading (redundant per-vertex) -> fp16 face colors ----
__global__ void shade_face_kernel(const float* __restrict__ vn,
                                  const float* __restrict__ vc,
                                  const float* __restrict__ sh,
                                  const int* __restrict__ faces,
                                  hf4* __restrict__ fc, int F) {
  int f = blockIdx.x * blockDim.x + threadIdx.x;
  if (f >= F) return;
  float s0r = sh[0] + kAmbient, s0g = sh[1] + kAmbient, s0b = sh[2] + kAmbient;
  int vid[3] = {faces[3 * f + 0], faces[3 * f + 1], faces[3 * f + 2]};
#pragma unroll
  for (int j = 0; j < 3; ++j) {
    int v = vid[j];
    float nx = vn[3 * v + 0], ny = vn[3 * v + 1], nz = vn[3 * v + 2];
    float nrm = fmaxf(sqrtf(nx * nx + ny * ny + nz * nz), 1e-6f);
    nx /= nrm; ny /= nrm; nz /= nrm;
    float Y1 = -kA1C1 * ny, Y2 = kA1C1 * nz, Y3 = -kA1C1 * nx;
    float Y4 =  kA2C2 * nx * ny, Y5 = -kA2C2 * ny * nz;
    float Y6 =  kA2C2 * (0.5f / 1.7320508075688772f) * (3.0f * nz * nz - 1.0f);
    float Y7 = -kA2C2 * nx * nz, Y8 = kA2C2 * 0.5f * (nx * nx - ny * ny);
    float r = kA0C0 * s0r + Y1 * sh[3] + Y2 * sh[6]  + Y3 * sh[9]  + Y4 * sh[12]
            + Y5 * sh[15] + Y6 * sh[18] + Y7 * sh[21] + Y8 * sh[24];
    float g = kA0C0 * s0g + Y1 * sh[4] + Y2 * sh[7]  + Y3 * sh[10] + Y4 * sh[13]
            + Y5 * sh[16] + Y6 * sh[19] + Y7 * sh[22] + Y8 * sh[25];
    float b = kA0C0 * s0b + Y1 * sh[5] + Y2 * sh[8]  + Y3 * sh[11] + Y4 * sh[14]
            + Y5 * sh[17] + Y6 * sh[20] + Y7 * sh[23] + Y8 * sh[26];
    hf4 o;
    o.x = (_Float16)(vc[3 * v + 0] * r);
    o.y = (_Float16)(vc[3 * v + 1] * g);
    o.z = (_Float16)(vc[3 * v + 2] * b);
    o.w = (_Float16)0.0f;
    fc[3 * f + j] = o;
  }
}

struct Sel {
  float w1, w2, delta, denom, alpha, maxz;
  int t1, f1, t2, f2, cnt;
};

// Pure-VALU phase: masks, sigmoid probs, z-softmax weights, branchless top-2.
__device__ __forceinline__ Sel phase1(int p, i4 fa, i4 fb, f4 za, f4 zb,
                                      f4 da, f4 db) {
  int   fk[8] = {fa.x, fa.y, fa.z, fa.w, fb.x, fb.y, fb.z, fb.w};
  float zz[8] = {za.x, za.y, za.z, za.w, zb.x, zb.y, zb.z, zb.w};
  float dd[8] = {da.x, da.y, da.z, da.w, db.x, db.y, db.z, db.w};
  float pr[8], zi[8];
  float maxz = kEps, alpha = 1.0f;
#pragma unroll
  for (int k = 0; k < 8; ++k) {
    bool m = fk[k] >= 0;
    float e = __expf(dd[k] * kInvSigma);
    float prv = m ? __builtin_amdgcn_rcpf(1.0f + e) : 0.0f;
    pr[k] = prv;
    alpha *= 1.0f - prv;
    float zv = m ? (kZfar - zz[k]) * kInvZrng : 0.0f;
    zi[k] = zv;
    maxz = fmaxf(maxz, zv);
  }
  Sel s;
  s.maxz  = maxz;
  s.alpha = alpha;
  s.delta = __expf((kEps - maxz) * kInvGamma);
  float denom = s.delta;
  float m1 = -1.0f, m2 = -1.0f;
  int k1 = 0, k2 = 0, f1 = 0, f2 = 0, cnt = 0;
#pragma unroll
  for (int k = 0; k < 8; ++k) {
    float edz = (zi[k] - maxz) * kInvGamma;
    float w = (edz > kExpCut) ? pr[k] * __expf(edz) : 0.0f;
    denom += w;
    cnt += (w != 0.0f) ? 1 : 0;
    bool g1 = w > m1, g2 = w > m2;
    m2 = g1 ? m1 : (g2 ? w : m2);
    k2 = g1 ? k1 : (g2 ? k : k2);
    f2 = g1 ? f1 : (g2 ? fk[k] : f2);
    m1 = g1 ? w : m1;
    k1 = g1 ? k : k1;
    f1 = g1 ? fk[k] : f1;
  }
  s.denom = denom;
  s.w1 = fmaxf(m1, 0.0f);
  s.w2 = fmaxf(m2, 0.0f);
  s.t1 = 8 * p + k1;  s.f1 = max(f1, 0);
  s.t2 = 8 * p + k2;  s.f2 = max(f2, 0);
  s.cnt = cnt;
  return s;
}

// Exact fallback for >=3 selected layers (~0.15% of pixels): full recompute.
__device__ __forceinline__ void slowpath(int p, i4 fa, i4 fb, f4 za, f4 zb,
                                         f4 da, f4 db, float maxz,
                                         const float* __restrict__ bary,
                                         const hf4* __restrict__ fc,
                                         float& cr, float& cg, float& cb) {
  int   fk[8] = {fa.x, fa.y, fa.z, fa.w, fb.x, fb.y, fb.z, fb.w};
  float zz[8] = {za.x, za.y, za.z, za.w, zb.x, zb.y, zb.z, zb.w};
  float dd[8] = {da.x, da.y, da.z, da.w, db.x, db.y, db.z, db.w};
  cr = cg = cb = 0.0f;
#pragma unroll
  for (int k = 0; k < 8; ++k) {
    bool m = fk[k] >= 0;
    float e = __expf(dd[k] * kInvSigma);
    float prv = m ? __builtin_amdgcn_rcpf(1.0f + e) : 0.0f;
    float zv = m ? (kZfar - zz[k]) * kInvZrng : 0.0f;
    float edz = (zv - maxz) * kInvGamma;
    float w = (edz > kExpCut) ? prv * __expf(edz) : 0.0f;
    if (w != 0.0f) {
      int t = 8 * p + k;
      float b0 = bary[3 * t + 0], b1 = bary[3 * t + 1], b2 = bary[3 * t + 2];
      hf4 v0 = fc[3 * fk[k] + 0];
      hf4 v1 = fc[3 * fk[k] + 1];
      hf4 v2 = fc[3 * fk[k] + 2];
      cr += w * (b0 * (float)v0.x + b1 * (float)v1.x + b2 * (float)v2.x);
      cg += w * (b0 * (float)v0.y + b1 * (float)v1.y + b2 * (float)v2.y);
      cb += w * (b0 * (float)v0.z + b1 * (float)v1.z + b2 * (float)v2.z);
    }
  }
}

// ---- Pass B: 2 pixels/thread, upfront stream loads, branchless top-2 gather ----
__global__ void __launch_bounds__(256, 4) blend_kernel(
    const float* __restrict__ bary,
    const f4* __restrict__ zb4,
    const f4* __restrict__ ds4,
    const i4* __restrict__ pf4,
    const hf4* __restrict__ fc,
    f4* __restrict__ out, int Phalf) {
  int t = blockIdx.x * blockDim.x + threadIdx.x;
  if (t >= Phalf) return;
  int p0 = t, p1 = t + Phalf;

  // 12 independent stream loads — issue them all before any compute.
  i4 fA0 = __builtin_nontemporal_load(pf4 + 2 * p0);
  i4 fA1 = __builtin_nontemporal_load(pf4 + 2 * p0 + 1);
  i4 fB0 = __builtin_nontemporal_load(pf4 + 2 * p1);
  i4 fB1 = __builtin_nontemporal_load(pf4 + 2 * p1 + 1);
  f4 zA0 = __builtin_nontemporal_load(zb4 + 2 * p0);
  f4 zA1 = __builtin_nontemporal_load(zb4 + 2 * p0 + 1);
  f4 zB0 = __builtin_nontemporal_load(zb4 + 2 * p1);
  f4 zB1 = __builtin_nontemporal_load(zb4 + 2 * p1 + 1);
  f4 dA0 = __builtin_nontemporal_load(ds4 + 2 * p0);
  f4 dA1 = __builtin_nontemporal_load(ds4 + 2 * p0 + 1);
  f4 dB0 = __builtin_nontemporal_load(ds4 + 2 * p1);
  f4 dB1 = __builtin_nontemporal_load(ds4 + 2 * p1 + 1);

  Sel sA = phase1(p0, fA0, fA1, zA0, zA1, dA0, dA1);
  Sel sB = phase1(p1, fB0, fB1, zB0, zB1, dB0, dB1);

  // Branchless gathers for both pixels' top-2 — 4 bary + 12 fc loads, all
  // independent, issued as one cluster.
  const float* bA1 = bary + 3 * sA.t1;
  const float* bA2 = bary + 3 * sA.t2;
  const float* bB1 = bary + 3 * sB.t1;
  const float* bB2 = bary + 3 * sB.t2;
  float a1b0 = bA1[0], a1b1 = bA1[1], a1b2 = bA1[2];
  float a2b0 = bA2[0], a2b1 = bA2[1], a2b2 = bA2[2];
  float b1b0 = bB1[0], b1b1 = bB1[1], b1b2 = bB1[2];
  float b2b0 = bB2[0], b2b1 = bB2[1], b2b2 = bB2[2];
  hf4 A1v0 = fc[3 * sA.f1 + 0], A1v1 = fc[3 * sA.f1 + 1], A1v2 = fc[3 * sA.f1 + 2];
  hf4 A2v0 = fc[3 * sA.f2 + 0], A2v1 = fc[3 * sA.f2 + 1], A2v2 = fc[3 * sA.f2 + 2];
  hf4 B1v0 = fc[3 * sB.f1 + 0], B1v1 = fc[3 * sB.f1 + 1], B1v2 = fc[3 * sB.f1 + 2];
  hf4 B2v0 = fc[3 * sB.f2 + 0], B2v1 = fc[3 * sB.f2 + 1], B2v2 = fc[3 * sB.f2 + 2];

  float crA = sA.w1 * (a1b0 * (float)A1v0.x + a1b1 * (float)A1v1.x + a1b2 * (float)A1v2.x)
            + sA.w2 * (a2b0 * (float)A2v0.x + a2b1 * (float)A2v1.x + a2b2 * (float)A2v2.x);
  float cgA = sA.w1 * (a1b0 * (float)A1v0.y + a1b1 * (float)A1v1.y + a1b2 * (float)A1v2.y)
            + sA.w2 * (a2b0 * (float)A2v0.y + a2b1 * (float)A2v1.y + a2b2 * (float)A2v2.y);
  float cbA = sA.w1 * (a1b0 * (float)A1v0.z + a1b1 * (float)A1v1.z + a1b2 * (float)A1v2.z)
            + sA.w2 * (a2b0 * (float)A2v0.z + a2b1 * (float)A2v1.z + a2b2 * (float)A2v2.z);
  float crB = sB.w1 * (b1b0 * (float)B1v0.x + b1b1 * (float)B1v1.x + b1b2 * (float)B1v2.x)
            + sB.w2 * (b2b0 * (float)B2v0.x + b2b1 * (float)B2v1.x + b2b2 * (float)B2v2.x);
  float cgB = sB.w1 * (b1b0 * (float)B1v0.y + b1b1 * (float)B1v1.y + b1b2 * (float)B1v2.y)
            + sB.w2 * (b2b0 * (float)B2v0.y + b2b1 * (float)B2v1.y + b2b2 * (float)B2v2.y);
  float cbB = sB.w1 * (b1b0 * (float)B1v0.z + b1b1 * (float)B1v1.z + b1b2 * (float)B1v2.z)
            + sB.w2 * (b2b0 * (float)B2v0.z + b2b1 * (float)B2v1.z + b2b2 * (float)B2v2.z);

  // Rare exact path: >=3 layers carry nonzero weight (~0.15% of pixels).
  if (sA.cnt > 2)
    slowpath(p0, fA0, fA1, zA0, zA1, dA0, dA1, sA.maxz, bary, fc, crA, cgA, cbA);
  if (sB.cnt > 2)
    slowpath(p1, fB0, fB1, zB0, zB1, dB0, dB1, sB.maxz, bary, fc, crB, cgB, cbB);

  float rdA = __builtin_amdgcn_rcpf(sA.denom);
  float rdB = __builtin_amdgcn_rcpf(sB.denom);
  f4 oA, oB;
  oA.x = (crA + sA.delta) * rdA;   // BG = (1,1,1)
  oA.y = (cgA + sA.delta) * rdA;
  oA.z = (cbA + sA.delta) * rdA;
  oA.w = 1.0f - sA.alpha;
  oB.x = (crB + sB.delta) * rdB;
  oB.y = (cgB + sB.delta) * rdB;
  oB.z = (cbB + sB.delta) * rdB;
  oB.w = 1.0f - sB.alpha;
  __builtin_nontemporal_store(oA, out + p0);
  __builtin_nontemporal_store(oB, out + p1);
}

}  // namespace

extern "C" void kernel_launch(void* const* d_in, const int* in_sizes, int n_in,
                              void* d_out, int out_size, void* d_ws, size_t ws_size,
                              hipStream_t stream) {
  const float* vn    = (const float*)d_in[0];
  const float* vc    = (const float*)d_in[1];
  const float* sh    = (const float*)d_in[2];
  const float* bary  = (const float*)d_in[3];
  const float* zbuf  = (const float*)d_in[4];
  const float* dists = (const float*)d_in[5];
  const int*   faces = (const int*)d_in[6];
  const int*   p2f   = (const int*)d_in[7];

  const int F = in_sizes[6] / 3;
  const int P = in_sizes[4] / 8;   // N*H*W pixels (K = 8)
  const int Phalf = P / 2;

  hf4* fc = (hf4*)d_ws;            // F * 24B = 4.8 MB

  shade_face_kernel<<<(F + 255) / 256, 256, 0, stream>>>(vn, vc, sh, faces, fc, F);
  blend_kernel<<<(Phalf + 255) / 256, 256, 0, stream>>>(
      bary, (const f4*)zbuf, (const f4*)dists, (const i4*)p2f, fc, (f4*)d_out, Phalf);
}